// Round 11
// baseline (536.930 us; speedup 1.0000x reference)
//
#include <hip/hip_runtime.h>
#include <math.h>

#define FEAT 256
#define RANKK 16
#define CAND_CAP 131072
#define TIE_CAP 2048
#define NBK_MAX 512   // max buckets (nhe/256)
#define PB_CHUNK 8192
#define SPLIT 4       // blocks per bucket in bucket_score
#define PRJ_NODES 64  // nodes per proj block (2n x 2r register tiling)
#define EH_BLOCKS 128
#define NW_BLOCKS 1024
#define TK_BLOCKS 1024  // topk_fused grid: exactly 4 blocks/CU x 256 CU co-resident
#define NK 4            // float4s per thread held in registers (covers n4 <= 1,048,576)

typedef unsigned long long u64;

static __device__ __forceinline__ u64 pack_pair(unsigned e_low, unsigned bits, unsigned idx) {
    // [63:56]=e&255, [55:26]=score bits (<2^30 since score<=1.0f), [25:0]=idx
    return ((u64)e_low << 56) | ((u64)bits << 26) | (u64)idx;
}
// vlist entry: [63:40]=v (24b), [31:8]=idx (24b), [7:0]=e&255
static __device__ __forceinline__ u64 pack_v(unsigned v, unsigned idx, unsigned e_low) {
    return ((u64)v << 40) | ((u64)idx << 8) | (u64)e_low;
}

// ========== K1: prep_all = ehist(+scan) | gather_ef | proj, split by block range ==========
__global__ __launch_bounds__(256) void prep_all(
        const int* __restrict__ E_idx, unsigned* __restrict__ bucketCnt,
        unsigned* __restrict__ bucketBase, unsigned* __restrict__ cursor,
        unsigned* __restrict__ ticket, int nnz,
        const float4* __restrict__ ef, const int* __restrict__ edge_ids,
        float4* __restrict__ ef2, int nhe,
        const float* __restrict__ x, const float* __restrict__ Wm,
        float* __restrict__ proj, int n_nodes, int G) {
    __shared__ float smem[12608];   // overlaid: proj tiles / ehist hist+scan
    __shared__ unsigned isLast;
    int t = threadIdx.x;
    int bid = blockIdx.x;

    if (bid < EH_BLOCKS) {
        unsigned* h  = (unsigned*)smem;            // 512
        unsigned* ps = ((unsigned*)smem) + 512;    // 256
        for (int j = t; j < NBK_MAX; j += 256) h[j] = 0;
        __syncthreads();
        for (int i = bid * 256 + t; i < nnz; i += EH_BLOCKS * 256)
            atomicAdd(&h[((unsigned)E_idx[i]) >> 8], 1u);
        __syncthreads();
        for (int j = t; j < NBK_MAX; j += 256)
            if (h[j]) atomicAdd(&bucketCnt[j], h[j]);
        __threadfence();
        if (t == 0) isLast = (atomicAdd(ticket, 1u) == EH_BLOCKS - 1) ? 1u : 0u;
        __syncthreads();
        if (!isLast) return;
        unsigned a0 = atomicAdd(&bucketCnt[2 * t], 0u);
        unsigned a1 = atomicAdd(&bucketCnt[2 * t + 1], 0u);
        unsigned pairsum = a0 + a1;
        ps[t] = pairsum;
        __syncthreads();
        for (int off = 1; off < 256; off <<= 1) {
            unsigned v = (t >= off) ? ps[t - off] : 0u;
            __syncthreads();
            ps[t] += v;
            __syncthreads();
        }
        unsigned excl = ps[t] - pairsum;
        bucketBase[2 * t] = excl;           cursor[2 * t] = excl;
        bucketBase[2 * t + 1] = excl + a0;  cursor[2 * t + 1] = excl + a0;
        if (t == 255) bucketBase[NBK_MAX] = ps[255];   // == nnz
        return;
    }
    if (bid < EH_BLOCKS + G) {
        int tt = (bid - EH_BLOCKS) * 256 + t;
        if (tt < nhe * 4) {
            int e = tt >> 2, c = tt & 3;
            ef2[(size_t)e * 4 + c] = ef[(size_t)edge_ids[e] * 4 + c];
        }
        return;
    }
    int pb = bid - EH_BLOCKS - G;
    float (*Ws)[FEAT + 4] = (float(*)[FEAT + 4])smem;            // 16x260
    float (*Xs)[128 + 4]  = (float(*)[128 + 4])(smem + 4160);    // 64x132
    const float4* x4 = (const float4*)x;
    const float4* w4 = (const float4*)Wm;
    for (int i = t; i < RANKK * 64; i += 256) {
        int r = i >> 6, c4 = i & 63;
        *(float4*)&Ws[r][c4 * 4] = w4[(size_t)r * 64 + c4];
    }
    int nodeBase = pb * PRJ_NODES;
    int np = t >> 3, rp = t & 7;
    int n0 = np * 2, r0 = rp * 2;
    double a00 = 0.0, a01 = 0.0, a10 = 0.0, a11 = 0.0;
    for (int chunk = 0; chunk < 2; ++chunk) {
        __syncthreads();
        for (int i = t; i < PRJ_NODES * 32; i += 256) {
            int row = i >> 5, c4 = i & 31;
            int node = nodeBase + row;
            float4 v = make_float4(0.f, 0.f, 0.f, 0.f);
            if (node < n_nodes) v = x4[(size_t)node * 64 + chunk * 32 + c4];
            *(float4*)&Xs[row][c4 * 4] = v;
        }
        __syncthreads();
        int jw = chunk * 128;
        #pragma unroll 8
        for (int j4 = 0; j4 < 32; ++j4) {
            float4 xa = *(const float4*)&Xs[n0][j4 * 4];
            float4 xb = *(const float4*)&Xs[n0 + 1][j4 * 4];
            float4 wa = *(const float4*)&Ws[r0][jw + j4 * 4];
            float4 wb = *(const float4*)&Ws[r0 + 1][jw + j4 * 4];
            a00 += (double)xa.x * wa.x + (double)xa.y * wa.y + (double)xa.z * wa.z + (double)xa.w * wa.w;
            a01 += (double)xa.x * wb.x + (double)xa.y * wb.y + (double)xa.z * wb.z + (double)xa.w * wb.w;
            a10 += (double)xb.x * wa.x + (double)xb.y * wa.y + (double)xb.z * wa.z + (double)xb.w * wa.w;
            a11 += (double)xb.x * wb.x + (double)xb.y * wb.y + (double)xb.z * wb.z + (double)xb.w * wb.w;
        }
    }
    int nodeA = nodeBase + n0;
    int nodeB = nodeA + 1;
    if (nodeA < n_nodes) {
        proj[(size_t)nodeA * RANKK + r0]     = (float)a00;
        proj[(size_t)nodeA * RANKK + r0 + 1] = (float)a01;
    }
    if (nodeB < n_nodes) {
        proj[(size_t)nodeB * RANKK + r0]     = (float)a10;
        proj[(size_t)nodeB * RANKK + r0 + 1] = (float)a11;
    }
}

// ========== K2: sort incidences into bucket order ==========
__global__ __launch_bounds__(256) void sort_kernel(const int* __restrict__ V_idx,
        const int* __restrict__ E_idx, u64* __restrict__ vlist,
        unsigned* __restrict__ cursor, int nnz, int nb) {
    __shared__ unsigned bh[NBK_MAX];
    int t = threadIdx.x;
    for (int j = t; j < NBK_MAX; j += 256) bh[j] = 0;
    __syncthreads();
    int base = blockIdx.x * PB_CHUNK;
    int nE = nnz - base;
    if (nE > PB_CHUNK) nE = PB_CHUNK;
    for (int o = t; o < nE; o += 256)
        atomicAdd(&bh[((unsigned)E_idx[base + o]) >> 8], 1u);
    __syncthreads();
    for (int b = t; b < nb; b += 256) {
        unsigned c = bh[b];
        bh[b] = c ? atomicAdd(&cursor[b], c) : 0u;
    }
    __syncthreads();
    for (int o = t; o < nE; o += 256) {
        int i = base + o;
        unsigned e = (unsigned)E_idx[i];
        unsigned v = (unsigned)V_idx[i];
        unsigned pos = atomicAdd(&bh[e >> 8], 1u);
        vlist[pos] = pack_v(v, (unsigned)i, e & 255u);
    }
}

// ========== K3 (primary): bucket-ordered score; ef2 tile in LDS; pairs in place ==========
__global__ __launch_bounds__(256) void bucket_score(
        const float4* __restrict__ proj4, const float4* __restrict__ ef4,
        const unsigned* __restrict__ bucketBase, u64* __restrict__ list,
        float* __restrict__ scores, int nhe) {
    __shared__ float efs[256][20];
    int t = threadIdx.x;
    int b = blockIdx.x >> 2;
    int part = blockIdx.x & (SPLIT - 1);
    for (int jj = t; jj < 1024; jj += 256) {
        int edge = (b << 8) + (jj >> 2);
        if (edge < nhe) {
            float4 v = ef4[(size_t)edge * 4 + (jj & 3)];
            *(float4*)&efs[jj >> 2][(jj & 3) * 4] = v;
        }
    }
    __syncthreads();
    unsigned n0 = bucketBase[b], n1 = bucketBase[b + 1];
    #pragma unroll 2
    for (unsigned j = n0 + (part << 8) + t; j < n1; j += SPLIT * 256) {
        u64 p = list[j];
        unsigned v   = (unsigned)(p >> 40);
        unsigned idx = (unsigned)(p >> 8) & 0xFFFFFFu;
        unsigned el  = (unsigned)(p & 255u);
        float4 p0 = proj4[(size_t)v * 4 + 0];
        float4 p1 = proj4[(size_t)v * 4 + 1];
        float4 p2 = proj4[(size_t)v * 4 + 2];
        float4 p3 = proj4[(size_t)v * 4 + 3];
        float4 f0 = *(const float4*)&efs[el][0];
        float4 f1 = *(const float4*)&efs[el][4];
        float4 f2 = *(const float4*)&efs[el][8];
        float4 f3 = *(const float4*)&efs[el][12];
        double acc = (double)p0.x * f0.x + (double)p0.y * f0.y + (double)p0.z * f0.z + (double)p0.w * f0.w
                   + (double)p1.x * f1.x + (double)p1.y * f1.y + (double)p1.z * f1.z + (double)p1.w * f1.w
                   + (double)p2.x * f2.x + (double)p2.y * f2.y + (double)p2.z * f2.z + (double)p2.w * f2.w
                   + (double)p3.x * f3.x + (double)p3.y * f3.y + (double)p3.z * f3.z + (double)p3.w * f3.w;
        float s = (float)(1.0 / (1.0 + exp(-acc)));
        scores[idx] = s;
        list[j] = pack_pair(el, __float_as_uint(s), idx);
    }
}

// ========== K3b/K3c (fallback when !wsBig): linear score + pair_build ==========
__global__ __launch_bounds__(256) void score_linear(
        const float4* __restrict__ proj4, const float4* __restrict__ ef4,
        const int* __restrict__ V_idx, const int* __restrict__ E_idx,
        float* __restrict__ scores, int nnz) {
    int stride = gridDim.x * blockDim.x;
    #pragma unroll 2
    for (int i = blockIdx.x * blockDim.x + threadIdx.x; i < nnz; i += stride) {
        int v = V_idx[i], e = E_idx[i];
        float4 p0 = proj4[(size_t)v * 4 + 0];
        float4 p1 = proj4[(size_t)v * 4 + 1];
        float4 p2 = proj4[(size_t)v * 4 + 2];
        float4 p3 = proj4[(size_t)v * 4 + 3];
        float4 f0 = ef4[(size_t)e * 4 + 0];
        float4 f1 = ef4[(size_t)e * 4 + 1];
        float4 f2 = ef4[(size_t)e * 4 + 2];
        float4 f3 = ef4[(size_t)e * 4 + 3];
        double acc = (double)p0.x * f0.x + (double)p0.y * f0.y + (double)p0.z * f0.z + (double)p0.w * f0.w
                   + (double)p1.x * f1.x + (double)p1.y * f1.y + (double)p1.z * f1.z + (double)p1.w * f1.w
                   + (double)p2.x * f2.x + (double)p2.y * f2.y + (double)p2.z * f2.z + (double)p2.w * f2.w
                   + (double)p3.x * f3.x + (double)p3.y * f3.y + (double)p3.z * f3.z + (double)p3.w * f3.w;
        scores[i] = (float)(1.0 / (1.0 + exp(-acc)));
    }
}
__global__ __launch_bounds__(256) void pair_build(const int* __restrict__ E_idx,
        const float* __restrict__ scores, u64* __restrict__ pairs,
        unsigned* __restrict__ cursor, int nnz, int nb) {
    __shared__ unsigned bh[NBK_MAX];
    for (int t = threadIdx.x; t < NBK_MAX; t += 256) bh[t] = 0;
    __syncthreads();
    int base = blockIdx.x * PB_CHUNK;
    int nE = nnz - base;
    if (nE > PB_CHUNK) nE = PB_CHUNK;
    for (int o = threadIdx.x; o < nE; o += 256)
        atomicAdd(&bh[((unsigned)E_idx[base + o]) >> 8], 1u);
    __syncthreads();
    for (int b = threadIdx.x; b < nb; b += 256) {
        unsigned c = bh[b];
        bh[b] = c ? atomicAdd(&cursor[b], c) : 0u;
    }
    __syncthreads();
    for (int o = threadIdx.x; o < nE; o += 256) {
        int i = base + o;
        unsigned e = (unsigned)E_idx[i];
        unsigned bits = __float_as_uint(scores[i]);
        unsigned pos = atomicAdd(&bh[e >> 8], 1u);
        pairs[pos] = pack_pair(e & 255u, bits, (unsigned)i);
    }
}

// ========== K4: topk_fused = hist1 + scan1 + compact + select (one dispatch) ==========
// Grid MUST be TK_BLOCKS with __launch_bounds__(256,4): 4 blocks/CU x 256 CU = 1024
// co-resident, so the spin barrier cannot deadlock. All cross-block reads use
// atomics or volatile (L1-bypass).
__global__ __launch_bounds__(256, 4) void topk_fused(
        const float4* __restrict__ scores4,
        unsigned* __restrict__ hist1g, unsigned* __restrict__ ticketA,
        unsigned* __restrict__ flagSel, unsigned* __restrict__ ticketB,
        unsigned* __restrict__ sel, const int* __restrict__ kptr,
        uint2* __restrict__ cand, unsigned* __restrict__ candCount,
        unsigned* __restrict__ tieList, int n4, int nnz) {
    __shared__ unsigned h[4096];
    __shared__ unsigned sfx[256];
    __shared__ unsigned h3[256];
    __shared__ unsigned ties[TIE_CAP];
    __shared__ unsigned sB2, sKrem2, sT, sM, tcnt, isLast;
    int t = threadIdx.x;
    int bid = blockIdx.x;
    int lane = t & 63;

    // ---- phase A: load scores into registers, histogram ----
    for (int j = t; j < 4096; j += 256) h[j] = 0;
    __syncthreads();
    float4 sv[NK];
    bool have[NK];
    unsigned r1016 = 0, r1015 = 0, r0 = 0;
    #pragma unroll
    for (int k = 0; k < NK; ++k) {
        int i = bid * 256 + t + k * (TK_BLOCKS * 256);
        have[k] = (i < n4);
        sv[k] = make_float4(0.f, 0.f, 0.f, 0.f);
        if (have[k]) sv[k] = scores4[i];
        if (have[k]) {
            unsigned bb[4] = {__float_as_uint(sv[k].x), __float_as_uint(sv[k].y),
                              __float_as_uint(sv[k].z), __float_as_uint(sv[k].w)};
            #pragma unroll
            for (int q = 0; q < 4; ++q) {
                unsigned b = bb[q] >> 20;
                if (b == 1016) ++r1016;
                else if (b == 1015) ++r1015;
                else if (b == 0) ++r0;
                else atomicAdd(&h[b], 1u);
            }
        }
    }
    // scalar tail (nnz % 4 elements), handled by the first few threads of block 0
    float stail = 0.f;
    bool haveTail = false;
    {
        int tpos = bid * 256 + t;
        int ntail = nnz - n4 * 4;
        if (tpos < ntail) {
            haveTail = true;
            stail = ((const float*)scores4)[n4 * 4 + tpos];
            unsigned b = __float_as_uint(stail) >> 20;
            if (b == 1016) ++r1016;
            else if (b == 1015) ++r1015;
            else if (b == 0) ++r0;
            else atomicAdd(&h[b], 1u);
        }
    }
    if (r1016) atomicAdd(&h[1016], r1016);
    if (r1015) atomicAdd(&h[1015], r1015);
    if (r0) atomicAdd(&h[0], r0);
    __syncthreads();
    for (int j = t; j < 4096; j += 256)
        if (h[j]) atomicAdd(&hist1g[j], h[j]);
    __threadfence();
    if (t == 0) isLast = (atomicAdd(ticketA, 1u) == TK_BLOCKS - 1) ? 1u : 0u;
    __syncthreads();

    // ---- scan1 in last-arriving block; others spin on flagSel ----
    if (isLast) {
        unsigned local[16];
        unsigned s = 0;
        #pragma unroll
        for (int j = 0; j < 16; ++j) { local[j] = atomicAdd(&hist1g[t * 16 + j], 0u); s += local[j]; }
        sfx[t] = s;
        __syncthreads();
        for (int off = 1; off < 256; off <<= 1) {
            unsigned add = (t + off < 256) ? sfx[t + off] : 0;
            __syncthreads();
            sfx[t] += add;
            __syncthreads();
        }
        unsigned krem = (unsigned)(*kptr);
        unsigned above = (t + 1 < 256) ? sfx[t + 1] : 0;
        if (above < krem && sfx[t] >= krem) {
            unsigned cum = above;
            int b = t * 16;
            for (int j = 15; j >= 0; --j) {
                unsigned cc = local[j];
                if (cum + cc >= krem) { b = t * 16 + j; break; }
                cum += cc;
            }
            sel[0] = krem - cum;
            sel[1] = ((unsigned)b) << 20;
        }
        __syncthreads();
        __threadfence();
        if (t == 0) atomicExch(flagSel, 1u);
    } else {
        if (t == 0) { while (atomicAdd(flagSel, 0u) == 0u) { } }
        __syncthreads();
    }
    unsigned pref = atomicAdd(&sel[1], 0u) >> 20;

    // ---- phase B: compact from registers ----
    #pragma unroll
    for (int k = 0; k < NK; ++k) {
        int i = bid * 256 + t + k * (TK_BLOCKS * 256);
        unsigned bb[4] = {__float_as_uint(sv[k].x), __float_as_uint(sv[k].y),
                          __float_as_uint(sv[k].z), __float_as_uint(sv[k].w)};
        #pragma unroll
        for (int q = 0; q < 4; ++q) {
            bool pred = have[k] && ((bb[q] >> 20) == pref);
            unsigned long long mask = __ballot(pred);
            if (mask) {
                int leader = __ffsll(mask) - 1;
                unsigned base = 0;
                if (lane == leader) base = atomicAdd(candCount, (unsigned)__popcll(mask));
                base = __shfl(base, leader, 64);
                if (pred) {
                    unsigned rank = __popcll(mask & ((1ull << lane) - 1ull));
                    unsigned pos = base + rank;
                    if (pos < CAND_CAP) cand[pos] = make_uint2(bb[q], (unsigned)(i * 4 + q));
                }
            }
        }
    }
    if (haveTail) {
        unsigned b = __float_as_uint(stail);
        if ((b >> 20) == pref) {
            unsigned pos = atomicAdd(candCount, 1u);
            if (pos < CAND_CAP) cand[pos] = make_uint2(b, (unsigned)(n4 * 4 + bid * 256 + t));
        }
    }
    __threadfence();
    if (t == 0) isLast = (atomicAdd(ticketB, 1u) == TK_BLOCKS - 1) ? 1u : 0u;
    __syncthreads();
    if (!isLast) return;

    // ---- select_small in last-arriving block (volatile reads bypass L1) ----
    volatile const uint2* vcand = (volatile const uint2*)cand;
    unsigned nc = atomicAdd(candCount, 0u);
    int n = (nc < CAND_CAP) ? (int)nc : CAND_CAP;
    unsigned krem = atomicAdd(&sel[0], 0u);
    unsigned prefbits = atomicAdd(&sel[1], 0u);

    for (int j = t; j < 4096; j += 256) h[j] = 0;
    if (t == 0) tcnt = 0;
    __syncthreads();
    for (int j = t; j < n; j += 256) atomicAdd(&h[(vcand[j].x >> 8) & 0xFFF], 1u);
    __syncthreads();

    unsigned local[16];
    unsigned s = 0;
    #pragma unroll
    for (int j = 0; j < 16; ++j) { local[j] = h[t * 16 + j]; s += local[j]; }
    sfx[t] = s;
    __syncthreads();
    for (int off = 1; off < 256; off <<= 1) {
        unsigned add = (t + off < 256) ? sfx[t + off] : 0;
        __syncthreads();
        sfx[t] += add;
        __syncthreads();
    }
    {
        unsigned above = (t + 1 < 256) ? sfx[t + 1] : 0;
        if (above < krem && sfx[t] >= krem) {
            unsigned cum = above;
            int b = t * 16;
            for (int j = 15; j >= 0; --j) {
                unsigned cc = local[j];
                if (cum + cc >= krem) { b = t * 16 + j; break; }
                cum += cc;
            }
            sB2 = (unsigned)b;
            sKrem2 = krem - cum;
        }
    }
    __syncthreads();

    h3[t] = 0;
    __syncthreads();
    unsigned b2 = sB2;
    for (int j = t; j < n; j += 256) {
        unsigned xx = vcand[j].x;
        if (((xx >> 8) & 0xFFF) == b2) atomicAdd(&h3[xx & 0xFF], 1u);
    }
    __syncthreads();
    sfx[t] = h3[t];
    __syncthreads();
    for (int off = 1; off < 256; off <<= 1) {
        unsigned add = (t + off < 256) ? sfx[t + off] : 0;
        __syncthreads();
        sfx[t] += add;
        __syncthreads();
    }
    {
        unsigned krem2 = sKrem2;
        unsigned above = (t + 1 < 256) ? sfx[t + 1] : 0;
        if (above < krem2 && sfx[t] >= krem2) {
            sT = prefbits | (b2 << 8) | (unsigned)t;
            sM = krem2 - above;
        }
    }
    __syncthreads();

    unsigned T = sT;
    for (int j = t; j < n; j += 256) {
        uint2 cj;
        cj.x = vcand[j].x;
        cj.y = vcand[j].y;
        if (cj.x == T) {
            unsigned p = atomicAdd(&tcnt, 1u);
            if (p < TIE_CAP) ties[p] = cj.y;
        }
    }
    __syncthreads();
    if (t == 0) {
        unsigned cnt = (tcnt < TIE_CAP) ? tcnt : TIE_CAP;
        for (unsigned a = 1; a < cnt; ++a) {
            unsigned key = ties[a];
            int bpos = (int)a - 1;
            while (bpos >= 0 && ties[bpos] > key) { ties[bpos + 1] = ties[bpos]; --bpos; }
            ties[bpos + 1] = key;
        }
        unsigned m = sM;
        if (m > cnt) m = cnt;
        sel[2] = T;
        sel[3] = m;
        for (unsigned j = 0; j < m; ++j) tieList[j] = ties[j];
    }
}

// ========== K4b/c/d (fallback for oversized nnz): separate hist/scan/compact/select ==========
__global__ __launch_bounds__(256) void hist1scan(const float4* __restrict__ scores4,
        unsigned* __restrict__ hist1g, unsigned* __restrict__ ticket,
        unsigned* __restrict__ sel, const int* __restrict__ kptr, int n4, int nnz) {
    __shared__ unsigned h[4096];
    __shared__ unsigned sfx[256];
    __shared__ unsigned isLast;
    int t = threadIdx.x;
    for (int j = t; j < 4096; j += 256) h[j] = 0;
    __syncthreads();
    unsigned r1016 = 0, r1015 = 0, r0 = 0;
    int stride = gridDim.x * 256;
    for (int i = blockIdx.x * 256 + t; i < n4; i += stride) {
        float4 sv = scores4[i];
        unsigned bb[4] = {__float_as_uint(sv.x), __float_as_uint(sv.y),
                          __float_as_uint(sv.z), __float_as_uint(sv.w)};
        #pragma unroll
        for (int q = 0; q < 4; ++q) {
            unsigned b = bb[q] >> 20;
            if (b == 1016) ++r1016;
            else if (b == 1015) ++r1015;
            else if (b == 0) ++r0;
            else atomicAdd(&h[b], 1u);
        }
    }
    for (int i = n4 * 4 + blockIdx.x * 256 + t; i < nnz; i += stride) {
        unsigned b = __float_as_uint(((const float*)scores4)[i]) >> 20;
        if (b == 1016) ++r1016;
        else if (b == 1015) ++r1015;
        else if (b == 0) ++r0;
        else atomicAdd(&h[b], 1u);
    }
    if (r1016) atomicAdd(&h[1016], r1016);
    if (r1015) atomicAdd(&h[1015], r1015);
    if (r0) atomicAdd(&h[0], r0);
    __syncthreads();
    for (int j = t; j < 4096; j += 256)
        if (h[j]) atomicAdd(&hist1g[j], h[j]);
    __threadfence();
    if (t == 0) isLast = (atomicAdd(ticket, 1u) == gridDim.x - 1) ? 1u : 0u;
    __syncthreads();
    if (!isLast) return;
    unsigned local[16];
    unsigned s = 0;
    #pragma unroll
    for (int j = 0; j < 16; ++j) { local[j] = atomicAdd(&hist1g[t * 16 + j], 0u); s += local[j]; }
    sfx[t] = s;
    __syncthreads();
    for (int off = 1; off < 256; off <<= 1) {
        unsigned add = (t + off < 256) ? sfx[t + off] : 0;
        __syncthreads();
        sfx[t] += add;
        __syncthreads();
    }
    unsigned krem = (unsigned)(*kptr);
    unsigned above = (t + 1 < 256) ? sfx[t + 1] : 0;
    if (above < krem && sfx[t] >= krem) {
        unsigned cum = above;
        int b = t * 16;
        for (int j = 15; j >= 0; --j) {
            unsigned cc = local[j];
            if (cum + cc >= krem) { b = t * 16 + j; break; }
            cum += cc;
        }
        sel[0] = krem - cum;
        sel[1] = ((unsigned)b) << 20;
    }
}
__global__ void compact_kernel(const float4* __restrict__ scores4,
                               const unsigned* __restrict__ sel,
                               uint2* __restrict__ cand, unsigned* __restrict__ candCount,
                               int n4, int nnz) {
    unsigned pref = sel[1] >> 20;
    int tid = blockIdx.x * blockDim.x + threadIdx.x;
    int stride = gridDim.x * blockDim.x;
    int lane = threadIdx.x & 63;
    int niter = (n4 + stride - 1) / stride;
    for (int kk = 0; kk < niter; ++kk) {
        int i = tid + kk * stride;
        bool inb = (i < n4);
        float4 sv = make_float4(0.f, 0.f, 0.f, 0.f);
        if (inb) sv = scores4[i];
        unsigned bb[4] = {__float_as_uint(sv.x), __float_as_uint(sv.y),
                          __float_as_uint(sv.z), __float_as_uint(sv.w)};
        #pragma unroll
        for (int q = 0; q < 4; ++q) {
            bool pred = inb && ((bb[q] >> 20) == pref);
            unsigned long long mask = __ballot(pred);
            if (mask) {
                int leader = __ffsll(mask) - 1;
                unsigned base = 0;
                if (lane == leader) base = atomicAdd(candCount, (unsigned)__popcll(mask));
                base = __shfl(base, leader, 64);
                if (pred) {
                    unsigned rank = __popcll(mask & ((1ull << lane) - 1ull));
                    unsigned pos = base + rank;
                    if (pos < CAND_CAP) cand[pos] = make_uint2(bb[q], (unsigned)(i * 4 + q));
                }
            }
        }
    }
    for (int i = n4 * 4 + tid; i < nnz; i += stride) {
        unsigned b = __float_as_uint(((const float*)scores4)[i]);
        if ((b >> 20) == pref) {
            unsigned pos = atomicAdd(candCount, 1u);
            if (pos < CAND_CAP) cand[pos] = make_uint2(b, (unsigned)i);
        }
    }
}
__global__ __launch_bounds__(256) void select_small(const uint2* __restrict__ cand,
                            const unsigned* __restrict__ candCount,
                            unsigned* __restrict__ sel, unsigned* __restrict__ tieList) {
    __shared__ unsigned h2[4096];
    __shared__ unsigned sfx[256];
    __shared__ unsigned sB2, sKrem2, sT, sM;
    __shared__ unsigned h3[256];
    __shared__ unsigned ties[TIE_CAP];
    __shared__ unsigned tcnt;
    int t = threadIdx.x;
    unsigned nc = *candCount;
    int n = (nc < CAND_CAP) ? (int)nc : CAND_CAP;
    unsigned krem = sel[0];
    unsigned pref = sel[1];
    for (int j = t; j < 4096; j += 256) h2[j] = 0;
    if (t == 0) tcnt = 0;
    __syncthreads();
    for (int j = t; j < n; j += 256) atomicAdd(&h2[(cand[j].x >> 8) & 0xFFF], 1u);
    __syncthreads();
    unsigned local[16];
    unsigned s = 0;
    #pragma unroll
    for (int j = 0; j < 16; ++j) { local[j] = h2[t * 16 + j]; s += local[j]; }
    sfx[t] = s;
    __syncthreads();
    for (int off = 1; off < 256; off <<= 1) {
        unsigned add = (t + off < 256) ? sfx[t + off] : 0;
        __syncthreads();
        sfx[t] += add;
        __syncthreads();
    }
    {
        unsigned above = (t + 1 < 256) ? sfx[t + 1] : 0;
        if (above < krem && sfx[t] >= krem) {
            unsigned cum = above;
            int b = t * 16;
            for (int j = 15; j >= 0; --j) {
                unsigned cc = local[j];
                if (cum + cc >= krem) { b = t * 16 + j; break; }
                cum += cc;
            }
            sB2 = (unsigned)b;
            sKrem2 = krem - cum;
        }
    }
    __syncthreads();
    h3[t] = 0;
    __syncthreads();
    unsigned b2 = sB2;
    for (int j = t; j < n; j += 256) {
        unsigned x = cand[j].x;
        if (((x >> 8) & 0xFFF) == b2) atomicAdd(&h3[x & 0xFF], 1u);
    }
    __syncthreads();
    sfx[t] = h3[t];
    __syncthreads();
    for (int off = 1; off < 256; off <<= 1) {
        unsigned add = (t + off < 256) ? sfx[t + off] : 0;
        __syncthreads();
        sfx[t] += add;
        __syncthreads();
    }
    {
        unsigned krem2 = sKrem2;
        unsigned above = (t + 1 < 256) ? sfx[t + 1] : 0;
        if (above < krem2 && sfx[t] >= krem2) {
            sT = pref | (b2 << 8) | (unsigned)t;
            sM = krem2 - above;
        }
    }
    __syncthreads();
    unsigned T = sT;
    for (int j = t; j < n; j += 256) {
        if (cand[j].x == T) {
            unsigned p = atomicAdd(&tcnt, 1u);
            if (p < TIE_CAP) ties[p] = cand[j].y;
        }
    }
    __syncthreads();
    if (t == 0) {
        unsigned cnt = (tcnt < TIE_CAP) ? tcnt : TIE_CAP;
        for (unsigned a = 1; a < cnt; ++a) {
            unsigned key = ties[a];
            int bpos = (int)a - 1;
            while (bpos >= 0 && ties[bpos] > key) { ties[bpos + 1] = ties[bpos]; --bpos; }
            ties[bpos + 1] = key;
        }
        unsigned m = sM;
        if (m > cnt) m = cnt;
        sel[2] = T;
        sel[3] = m;
        for (unsigned j = 0; j < m; ++j) tieList[j] = ties[j];
    }
}

// ========== K5 (wsHuge): fused edge_final + write_hard — pairs in d_ws, no aliasing ==========
__global__ __launch_bounds__(256) void final_combo(const u64* __restrict__ pairs,
        const unsigned* __restrict__ bucketBase, const unsigned* __restrict__ sel,
        const unsigned* __restrict__ tieList, const float4* __restrict__ scores4,
        float* __restrict__ eprob, float* __restrict__ esoft, float* __restrict__ ehard,
        float4* __restrict__ hard4, float4* __restrict__ soft4,
        int nb, int n4, int nnz, int nhe) {
    __shared__ float ss[256];
    __shared__ unsigned cc[256];
    __shared__ unsigned hh[256];
    __shared__ unsigned ties[TIE_CAP];
    unsigned T = sel[2];
    unsigned m = sel[3];
    if (m > TIE_CAP) m = TIE_CAP;
    int t = threadIdx.x;
    for (int j = t; j < (int)m; j += 256) ties[j] = tieList[j];

    if ((int)blockIdx.x < nb) {
        ss[t] = 0.f; cc[t] = 0u; hh[t] = 0u;
        __syncthreads();
        int b = blockIdx.x;
        unsigned n0 = bucketBase[b], n1 = bucketBase[b + 1];
        for (unsigned j = n0 + t; j < n1; j += 256) {
            u64 p = pairs[j];
            unsigned el = (unsigned)(p >> 56);
            unsigned bits = (unsigned)(p >> 26) & 0x3FFFFFFFu;
            atomicAdd(&ss[el], __uint_as_float(bits));
            atomicAdd(&cc[el], 1u);
            bool keep = bits > T;
            if (bits == T) {
                unsigned idx = (unsigned)(p & 0x3FFFFFFu);
                int lo = 0, hi = (int)m - 1;
                keep = false;
                while (lo <= hi) {
                    int mid = (lo + hi) >> 1;
                    unsigned v = ties[mid];
                    if (v == idx) { keep = true; break; }
                    if (v < idx) lo = mid + 1; else hi = mid - 1;
                }
            }
            if (keep) atomicAdd(&hh[el], 1u);
        }
        __syncthreads();
        int e = blockIdx.x * 256 + t;
        if (e < nhe) {
            float c = fmaxf((float)cc[t], 1.0f);
            eprob[e] = ss[t] / c;
            esoft[e] = (float)hh[t] / c;
            ehard[e] = (hh[t] > 0) ? 1.0f : 0.0f;
        }
        return;
    }
    __syncthreads();
    int tid = (blockIdx.x - nb) * 256 + t;
    int stride = NW_BLOCKS * 256;
    for (int i = tid; i < n4; i += stride) {
        float4 sv = scores4[i];
        unsigned bb[4] = {__float_as_uint(sv.x), __float_as_uint(sv.y),
                          __float_as_uint(sv.z), __float_as_uint(sv.w)};
        float hv[4];
        #pragma unroll
        for (int q = 0; q < 4; ++q) {
            bool keep = (bb[q] > T);
            if (bb[q] == T) {
                unsigned idx = (unsigned)(i * 4 + q);
                int lo = 0, hi = (int)m - 1;
                keep = false;
                while (lo <= hi) {
                    int mid = (lo + hi) >> 1;
                    unsigned v = ties[mid];
                    if (v == idx) { keep = true; break; }
                    if (v < idx) lo = mid + 1; else hi = mid - 1;
                }
            }
            hv[q] = keep ? 1.0f : 0.0f;
        }
        float4 outv = make_float4(hv[0], hv[1], hv[2], hv[3]);
        hard4[i] = outv;
        soft4[i] = outv;
    }
    const float* sc = (const float*)scores4;
    float* hard = (float*)hard4;
    float* soft = (float*)soft4;
    for (int i = n4 * 4 + tid; i < nnz; i += stride) {
        unsigned b = __float_as_uint(sc[i]);
        bool keep = (b > T);
        if (b == T) {
            unsigned idx = (unsigned)i;
            int lo = 0, hi = (int)m - 1;
            keep = false;
            while (lo <= hi) {
                int mid = (lo + hi) >> 1;
                unsigned v = ties[mid];
                if (v == idx) { keep = true; break; }
                if (v < idx) lo = mid + 1; else hi = mid - 1;
            }
        }
        float hvv = keep ? 1.0f : 0.0f;
        hard[i] = hvv;
        soft[i] = hvv;
    }
}

// ========== K5b/K5c (fallback when pairs aliases soft/hard): sequential versions ==========
__global__ __launch_bounds__(256) void edge_final(const u64* __restrict__ pairs,
        const unsigned* __restrict__ bucketBase, const unsigned* __restrict__ sel,
        const unsigned* __restrict__ tieList,
        float* __restrict__ eprob, float* __restrict__ esoft, float* __restrict__ ehard,
        int nhe) {
    __shared__ float ss[256];
    __shared__ unsigned cc[256];
    __shared__ unsigned hh[256];
    __shared__ unsigned ties[TIE_CAP];
    unsigned T = sel[2];
    unsigned m = sel[3];
    if (m > TIE_CAP) m = TIE_CAP;
    int t = threadIdx.x;
    ss[t] = 0.f; cc[t] = 0u; hh[t] = 0u;
    for (int j = t; j < (int)m; j += 256) ties[j] = tieList[j];
    __syncthreads();
    int b = blockIdx.x;
    unsigned n0 = bucketBase[b], n1 = bucketBase[b + 1];
    for (unsigned j = n0 + t; j < n1; j += 256) {
        u64 p = pairs[j];
        unsigned el = (unsigned)(p >> 56);
        unsigned bits = (unsigned)(p >> 26) & 0x3FFFFFFFu;
        atomicAdd(&ss[el], __uint_as_float(bits));
        atomicAdd(&cc[el], 1u);
        bool keep = bits > T;
        if (bits == T) {
            unsigned idx = (unsigned)(p & 0x3FFFFFFu);
            int lo = 0, hi = (int)m - 1;
            keep = false;
            while (lo <= hi) {
                int mid = (lo + hi) >> 1;
                unsigned v = ties[mid];
                if (v == idx) { keep = true; break; }
                if (v < idx) lo = mid + 1; else hi = mid - 1;
            }
        }
        if (keep) atomicAdd(&hh[el], 1u);
    }
    __syncthreads();
    int e = b * 256 + t;
    if (e < nhe) {
        float c = fmaxf((float)cc[t], 1.0f);
        eprob[e] = ss[t] / c;
        esoft[e] = (float)hh[t] / c;
        ehard[e] = (hh[t] > 0) ? 1.0f : 0.0f;
    }
}
__global__ __launch_bounds__(256) void write_hard(const float4* __restrict__ scores4,
                           const unsigned* __restrict__ sel,
                           const unsigned* __restrict__ tieList,
                           float4* __restrict__ hard4, float4* __restrict__ soft4,
                           int n4, int nnz) {
    __shared__ unsigned ties[TIE_CAP];
    unsigned T = sel[2];
    unsigned m = sel[3];
    if (m > TIE_CAP) m = TIE_CAP;
    for (int j = threadIdx.x; j < (int)m; j += blockDim.x) ties[j] = tieList[j];
    __syncthreads();
    int tid = blockIdx.x * blockDim.x + threadIdx.x;
    int stride = gridDim.x * blockDim.x;
    for (int i = tid; i < n4; i += stride) {
        float4 sv = scores4[i];
        unsigned bb[4] = {__float_as_uint(sv.x), __float_as_uint(sv.y),
                          __float_as_uint(sv.z), __float_as_uint(sv.w)};
        float hv[4];
        #pragma unroll
        for (int q = 0; q < 4; ++q) {
            bool keep = (bb[q] > T);
            if (bb[q] == T) {
                unsigned idx = (unsigned)(i * 4 + q);
                int lo = 0, hi = (int)m - 1;
                keep = false;
                while (lo <= hi) {
                    int mid = (lo + hi) >> 1;
                    unsigned v = ties[mid];
                    if (v == idx) { keep = true; break; }
                    if (v < idx) lo = mid + 1; else hi = mid - 1;
                }
            }
            hv[q] = keep ? 1.0f : 0.0f;
        }
        float4 outv = make_float4(hv[0], hv[1], hv[2], hv[3]);
        hard4[i] = outv;
        soft4[i] = outv;
    }
    const float* sc = (const float*)scores4;
    float* hard = (float*)hard4;
    float* soft = (float*)soft4;
    for (int i = n4 * 4 + tid; i < nnz; i += stride) {
        unsigned b = __float_as_uint(sc[i]);
        bool keep = (b > T);
        if (b == T) {
            unsigned idx = (unsigned)i;
            int lo = 0, hi = (int)m - 1;
            keep = false;
            while (lo <= hi) {
                int mid = (lo + hi) >> 1;
                unsigned v = ties[mid];
                if (v == idx) { keep = true; break; }
                if (v < idx) lo = mid + 1; else hi = mid - 1;
            }
        }
        float hvv = keep ? 1.0f : 0.0f;
        hard[i] = hvv;
        soft[i] = hvv;
    }
}

extern "C" void kernel_launch(void* const* d_in, const int* in_sizes, int n_in,
                              void* d_out, int out_size, void* d_ws, size_t ws_size,
                              hipStream_t stream) {
    const float* x        = (const float*)d_in[0];
    const float* Wm       = (const float*)d_in[1];
    const float* ef       = (const float*)d_in[2];
    const int*   V_idx    = (const int*)d_in[3];
    const int*   E_idx    = (const int*)d_in[4];
    const int*   edge_ids = (const int*)d_in[5];
    const int*   kptr     = (const int*)d_in[6];

    const int nnz     = in_sizes[3];
    const int nhe     = in_sizes[5];
    const int n_nodes = in_sizes[0] / FEAT;
    const int nb      = (nhe + 255) >> 8;

    float* out    = (float*)d_out;
    float* scores = out;
    float* soft   = out + (size_t)nnz;
    float* hard   = out + 2 * (size_t)nnz;
    float* eprob  = out + 3 * (size_t)nnz;
    float* esoft  = eprob + nhe;
    float* ehard  = esoft + nhe;

    uint2* cand = (uint2*)eprob;   // consumed by select before eprob is written

    // ---- aux zone in d_ws ----
    char* w = (char*)d_ws;
    unsigned* hist1      = (unsigned*)w;               // 4096 (zeroed)
    unsigned* bucketCnt  = hist1 + 4096;               // NBK_MAX (zeroed)
    unsigned* candCount  = bucketCnt + NBK_MAX;        // 1 (zeroed)
    unsigned* ticket1    = candCount + 1;              // 1 (zeroed)  prep_all
    unsigned* ticketA    = ticket1 + 1;                // 1 (zeroed)  topk phase A
    unsigned* ticketB    = ticketA + 1;                // 1 (zeroed)  topk phase B
    unsigned* flagSel    = ticketB + 1;                // 1 (zeroed)  sel-published flag
    unsigned* sel        = flagSel + 1;                // 8
    unsigned* tieList    = sel + 8;                    // TIE_CAP
    unsigned* bucketBase = tieList + TIE_CAP;          // NBK_MAX+1
    unsigned* cursor     = bucketBase + NBK_MAX + 1;   // NBK_MAX
    char* auxEnd = (char*)(cursor + NBK_MAX);
    size_t auxAligned = (((size_t)(auxEnd - w)) + 255) & ~(size_t)255;
    size_t zeroBytes = (size_t)(4096 + NBK_MAX + 5) * sizeof(unsigned);

    size_t ef2Bytes   = (size_t)nhe * RANKK * sizeof(float);
    size_t projBytes  = (size_t)n_nodes * RANKK * sizeof(float);
    size_t pairsBytes = (size_t)nnz * sizeof(u64);

    bool wsBig  = (ws_size >= auxAligned + ef2Bytes + projBytes);
    bool wsHuge = (ws_size >= auxAligned + ef2Bytes + projBytes + pairsBytes);

    float* ef2;
    float* proj;
    u64*   vlist;
    if (wsBig) {
        ef2  = (float*)(w + auxAligned);
        proj = (float*)(w + auxAligned + ef2Bytes);
        vlist = wsHuge ? (u64*)(w + auxAligned + ef2Bytes + projBytes) : (u64*)soft;
    } else {
        ef2  = hard;   // consumed by score before pairs scatter touches hard
        proj = hard + (size_t)nhe * RANKK;
        vlist = (u64*)soft;
    }

    hipMemsetAsync(w, 0, zeroBytes, stream);

    int G = (nhe * 4 + 255) / 256;
    int P = (n_nodes + PRJ_NODES - 1) / PRJ_NODES;
    prep_all<<<EH_BLOCKS + G + P, 256, 0, stream>>>(
        E_idx, bucketCnt, bucketBase, cursor, ticket1, nnz,
        (const float4*)ef, edge_ids, (float4*)ef2, nhe,
        x, Wm, proj, n_nodes, G);

    int nChunks = (nnz + PB_CHUNK - 1) / PB_CHUNK;
    if (wsBig) {
        sort_kernel<<<nChunks, 256, 0, stream>>>(V_idx, E_idx, vlist, cursor, nnz, nb);
        bucket_score<<<nb * SPLIT, 256, 0, stream>>>(
            (const float4*)proj, (const float4*)ef2, bucketBase, vlist, scores, nhe);
    } else {
        score_linear<<<2048, 256, 0, stream>>>(
            (const float4*)proj, (const float4*)ef2, V_idx, E_idx, scores, nnz);
        pair_build<<<nChunks, 256, 0, stream>>>(E_idx, scores, vlist, cursor, nnz, nb);
    }

    int n4 = nnz / 4;
    if (n4 <= NK * TK_BLOCKS * 256 && nnz - n4 * 4 <= TK_BLOCKS * 256) {
        topk_fused<<<TK_BLOCKS, 256, 0, stream>>>(
            (const float4*)scores, hist1, ticketA, flagSel, ticketB,
            sel, kptr, cand, candCount, tieList, n4, nnz);
    } else {
        hist1scan<<<128, 256, 0, stream>>>((const float4*)scores, hist1, ticketA,
                                           sel, kptr, n4, nnz);
        compact_kernel<<<1024, 256, 0, stream>>>(
            (const float4*)scores, sel, cand, candCount, n4, nnz);
        select_small<<<1, 256, 0, stream>>>(cand, candCount, sel, tieList);
    }

    if (wsHuge) {
        final_combo<<<nb + NW_BLOCKS, 256, 0, stream>>>(
            vlist, bucketBase, sel, tieList, (const float4*)scores,
            eprob, esoft, ehard, (float4*)hard, (float4*)soft, nb, n4, nnz, nhe);
    } else {
        edge_final<<<nb, 256, 0, stream>>>(vlist, bucketBase, sel, tieList,
                                           eprob, esoft, ehard, nhe);
        write_hard<<<1024, 256, 0, stream>>>(
            (const float4*)scores, sel, tieList, (float4*)hard, (float4*)soft, n4, nnz);
    }
}

// Round 12
// 445.737 us; speedup vs baseline: 1.2046x; 1.2046x over previous
//
#include <hip/hip_runtime.h>
#include <math.h>

#define FEAT 256
#define RANKK 16
#define CAND_CAP 131072
#define TIE_CAP 2048
#define NBK_MAX 512   // max buckets (nhe/256)
#define PB_CHUNK 8192
#define SPLIT 4       // blocks per bucket in bucket_score
#define PRJ_NODES 64  // nodes per proj block (2n x 2r register tiling)
#define EH_BLOCKS 128
#define NW_BLOCKS 1024

typedef unsigned long long u64;

static __device__ __forceinline__ u64 pack_pair(unsigned e_low, unsigned bits, unsigned idx) {
    // [63:56]=e&255, [55:26]=score bits (<2^30 since score<=1.0f), [25:0]=idx
    return ((u64)e_low << 56) | ((u64)bits << 26) | (u64)idx;
}
// vlist entry: [63:40]=v (24b), [31:8]=idx (24b), [7:0]=e&255
static __device__ __forceinline__ u64 pack_v(unsigned v, unsigned idx, unsigned e_low) {
    return ((u64)v << 40) | ((u64)idx << 8) | (u64)e_low;
}

// ========== K1: prep_all = ehist(+scan) | gather_ef | proj, split by block range ==========
__global__ __launch_bounds__(256) void prep_all(
        const int* __restrict__ E_idx, unsigned* __restrict__ bucketCnt,
        unsigned* __restrict__ bucketBase, unsigned* __restrict__ cursor,
        unsigned* __restrict__ ticket, int nnz,
        const float4* __restrict__ ef, const int* __restrict__ edge_ids,
        float4* __restrict__ ef2, int nhe,
        const float* __restrict__ x, const float* __restrict__ Wm,
        float* __restrict__ proj, int n_nodes, int G) {
    __shared__ float smem[12608];   // overlaid: proj tiles / ehist hist+scan
    __shared__ unsigned isLast;
    int t = threadIdx.x;
    int bid = blockIdx.x;

    if (bid < EH_BLOCKS) {
        unsigned* h  = (unsigned*)smem;            // 512
        unsigned* ps = ((unsigned*)smem) + 512;    // 256
        for (int j = t; j < NBK_MAX; j += 256) h[j] = 0;
        __syncthreads();
        for (int i = bid * 256 + t; i < nnz; i += EH_BLOCKS * 256)
            atomicAdd(&h[((unsigned)E_idx[i]) >> 8], 1u);
        __syncthreads();
        for (int j = t; j < NBK_MAX; j += 256)
            if (h[j]) atomicAdd(&bucketCnt[j], h[j]);
        __threadfence();
        if (t == 0) isLast = (atomicAdd(ticket, 1u) == EH_BLOCKS - 1) ? 1u : 0u;
        __syncthreads();
        if (!isLast) return;
        unsigned a0 = atomicAdd(&bucketCnt[2 * t], 0u);
        unsigned a1 = atomicAdd(&bucketCnt[2 * t + 1], 0u);
        unsigned pairsum = a0 + a1;
        ps[t] = pairsum;
        __syncthreads();
        for (int off = 1; off < 256; off <<= 1) {
            unsigned v = (t >= off) ? ps[t - off] : 0u;
            __syncthreads();
            ps[t] += v;
            __syncthreads();
        }
        unsigned excl = ps[t] - pairsum;
        bucketBase[2 * t] = excl;           cursor[2 * t] = excl;
        bucketBase[2 * t + 1] = excl + a0;  cursor[2 * t + 1] = excl + a0;
        if (t == 255) bucketBase[NBK_MAX] = ps[255];   // == nnz
        return;
    }
    if (bid < EH_BLOCKS + G) {
        int tt = (bid - EH_BLOCKS) * 256 + t;
        if (tt < nhe * 4) {
            int e = tt >> 2, c = tt & 3;
            ef2[(size_t)e * 4 + c] = ef[(size_t)edge_ids[e] * 4 + c];
        }
        return;
    }
    int pb = bid - EH_BLOCKS - G;
    float (*Ws)[FEAT + 4] = (float(*)[FEAT + 4])smem;            // 16x260
    float (*Xs)[128 + 4]  = (float(*)[128 + 4])(smem + 4160);    // 64x132
    const float4* x4 = (const float4*)x;
    const float4* w4 = (const float4*)Wm;
    for (int i = t; i < RANKK * 64; i += 256) {
        int r = i >> 6, c4 = i & 63;
        *(float4*)&Ws[r][c4 * 4] = w4[(size_t)r * 64 + c4];
    }
    int nodeBase = pb * PRJ_NODES;
    int np = t >> 3, rp = t & 7;
    int n0 = np * 2, r0 = rp * 2;
    double a00 = 0.0, a01 = 0.0, a10 = 0.0, a11 = 0.0;
    for (int chunk = 0; chunk < 2; ++chunk) {
        __syncthreads();
        for (int i = t; i < PRJ_NODES * 32; i += 256) {
            int row = i >> 5, c4 = i & 31;
            int node = nodeBase + row;
            float4 v = make_float4(0.f, 0.f, 0.f, 0.f);
            if (node < n_nodes) v = x4[(size_t)node * 64 + chunk * 32 + c4];
            *(float4*)&Xs[row][c4 * 4] = v;
        }
        __syncthreads();
        int jw = chunk * 128;
        #pragma unroll 8
        for (int j4 = 0; j4 < 32; ++j4) {
            float4 xa = *(const float4*)&Xs[n0][j4 * 4];
            float4 xb = *(const float4*)&Xs[n0 + 1][j4 * 4];
            float4 wa = *(const float4*)&Ws[r0][jw + j4 * 4];
            float4 wb = *(const float4*)&Ws[r0 + 1][jw + j4 * 4];
            a00 += (double)xa.x * wa.x + (double)xa.y * wa.y + (double)xa.z * wa.z + (double)xa.w * wa.w;
            a01 += (double)xa.x * wb.x + (double)xa.y * wb.y + (double)xa.z * wb.z + (double)xa.w * wb.w;
            a10 += (double)xb.x * wa.x + (double)xb.y * wa.y + (double)xb.z * wa.z + (double)xb.w * wa.w;
            a11 += (double)xb.x * wb.x + (double)xb.y * wb.y + (double)xb.z * wb.z + (double)xb.w * wb.w;
        }
    }
    int nodeA = nodeBase + n0;
    int nodeB = nodeA + 1;
    if (nodeA < n_nodes) {
        proj[(size_t)nodeA * RANKK + r0]     = (float)a00;
        proj[(size_t)nodeA * RANKK + r0 + 1] = (float)a01;
    }
    if (nodeB < n_nodes) {
        proj[(size_t)nodeB * RANKK + r0]     = (float)a10;
        proj[(size_t)nodeB * RANKK + r0 + 1] = (float)a11;
    }
}

// ========== K2: sort incidences into bucket order ==========
__global__ __launch_bounds__(256) void sort_kernel(const int* __restrict__ V_idx,
        const int* __restrict__ E_idx, u64* __restrict__ vlist,
        unsigned* __restrict__ cursor, int nnz, int nb) {
    __shared__ unsigned bh[NBK_MAX];
    int t = threadIdx.x;
    for (int j = t; j < NBK_MAX; j += 256) bh[j] = 0;
    __syncthreads();
    int base = blockIdx.x * PB_CHUNK;
    int nE = nnz - base;
    if (nE > PB_CHUNK) nE = PB_CHUNK;
    for (int o = t; o < nE; o += 256)
        atomicAdd(&bh[((unsigned)E_idx[base + o]) >> 8], 1u);
    __syncthreads();
    for (int b = t; b < nb; b += 256) {
        unsigned c = bh[b];
        bh[b] = c ? atomicAdd(&cursor[b], c) : 0u;
    }
    __syncthreads();
    for (int o = t; o < nE; o += 256) {
        int i = base + o;
        unsigned e = (unsigned)E_idx[i];
        unsigned v = (unsigned)V_idx[i];
        unsigned pos = atomicAdd(&bh[e >> 8], 1u);
        vlist[pos] = pack_v(v, (unsigned)i, e & 255u);
    }
}

// ========== K3 (primary): bucket-ordered score; ef2 tile in LDS; pairs in place ==========
__global__ __launch_bounds__(256) void bucket_score(
        const float4* __restrict__ proj4, const float4* __restrict__ ef4,
        const unsigned* __restrict__ bucketBase, u64* __restrict__ list,
        float* __restrict__ scores, int nhe) {
    __shared__ float efs[256][20];
    int t = threadIdx.x;
    int b = blockIdx.x >> 2;
    int part = blockIdx.x & (SPLIT - 1);
    for (int jj = t; jj < 1024; jj += 256) {
        int edge = (b << 8) + (jj >> 2);
        if (edge < nhe) {
            float4 v = ef4[(size_t)edge * 4 + (jj & 3)];
            *(float4*)&efs[jj >> 2][(jj & 3) * 4] = v;
        }
    }
    __syncthreads();
    unsigned n0 = bucketBase[b], n1 = bucketBase[b + 1];
    #pragma unroll 2
    for (unsigned j = n0 + (part << 8) + t; j < n1; j += SPLIT * 256) {
        u64 p = list[j];
        unsigned v   = (unsigned)(p >> 40);
        unsigned idx = (unsigned)(p >> 8) & 0xFFFFFFu;
        unsigned el  = (unsigned)(p & 255u);
        float4 p0 = proj4[(size_t)v * 4 + 0];
        float4 p1 = proj4[(size_t)v * 4 + 1];
        float4 p2 = proj4[(size_t)v * 4 + 2];
        float4 p3 = proj4[(size_t)v * 4 + 3];
        float4 f0 = *(const float4*)&efs[el][0];
        float4 f1 = *(const float4*)&efs[el][4];
        float4 f2 = *(const float4*)&efs[el][8];
        float4 f3 = *(const float4*)&efs[el][12];
        double acc = (double)p0.x * f0.x + (double)p0.y * f0.y + (double)p0.z * f0.z + (double)p0.w * f0.w
                   + (double)p1.x * f1.x + (double)p1.y * f1.y + (double)p1.z * f1.z + (double)p1.w * f1.w
                   + (double)p2.x * f2.x + (double)p2.y * f2.y + (double)p2.z * f2.z + (double)p2.w * f2.w
                   + (double)p3.x * f3.x + (double)p3.y * f3.y + (double)p3.z * f3.z + (double)p3.w * f3.w;
        float s = (float)(1.0 / (1.0 + exp(-acc)));
        scores[idx] = s;
        list[j] = pack_pair(el, __float_as_uint(s), idx);
    }
}

// ========== K3b/K3c (fallback when !wsBig): linear score + pair_build ==========
__global__ __launch_bounds__(256) void score_linear(
        const float4* __restrict__ proj4, const float4* __restrict__ ef4,
        const int* __restrict__ V_idx, const int* __restrict__ E_idx,
        float* __restrict__ scores, int nnz) {
    int stride = gridDim.x * blockDim.x;
    #pragma unroll 2
    for (int i = blockIdx.x * blockDim.x + threadIdx.x; i < nnz; i += stride) {
        int v = V_idx[i], e = E_idx[i];
        float4 p0 = proj4[(size_t)v * 4 + 0];
        float4 p1 = proj4[(size_t)v * 4 + 1];
        float4 p2 = proj4[(size_t)v * 4 + 2];
        float4 p3 = proj4[(size_t)v * 4 + 3];
        float4 f0 = ef4[(size_t)e * 4 + 0];
        float4 f1 = ef4[(size_t)e * 4 + 1];
        float4 f2 = ef4[(size_t)e * 4 + 2];
        float4 f3 = ef4[(size_t)e * 4 + 3];
        double acc = (double)p0.x * f0.x + (double)p0.y * f0.y + (double)p0.z * f0.z + (double)p0.w * f0.w
                   + (double)p1.x * f1.x + (double)p1.y * f1.y + (double)p1.z * f1.z + (double)p1.w * f1.w
                   + (double)p2.x * f2.x + (double)p2.y * f2.y + (double)p2.z * f2.z + (double)p2.w * f2.w
                   + (double)p3.x * f3.x + (double)p3.y * f3.y + (double)p3.z * f3.z + (double)p3.w * f3.w;
        scores[i] = (float)(1.0 / (1.0 + exp(-acc)));
    }
}
__global__ __launch_bounds__(256) void pair_build(const int* __restrict__ E_idx,
        const float* __restrict__ scores, u64* __restrict__ pairs,
        unsigned* __restrict__ cursor, int nnz, int nb) {
    __shared__ unsigned bh[NBK_MAX];
    for (int t = threadIdx.x; t < NBK_MAX; t += 256) bh[t] = 0;
    __syncthreads();
    int base = blockIdx.x * PB_CHUNK;
    int nE = nnz - base;
    if (nE > PB_CHUNK) nE = PB_CHUNK;
    for (int o = threadIdx.x; o < nE; o += 256)
        atomicAdd(&bh[((unsigned)E_idx[base + o]) >> 8], 1u);
    __syncthreads();
    for (int b = threadIdx.x; b < nb; b += 256) {
        unsigned c = bh[b];
        bh[b] = c ? atomicAdd(&cursor[b], c) : 0u;
    }
    __syncthreads();
    for (int o = threadIdx.x; o < nE; o += 256) {
        int i = base + o;
        unsigned e = (unsigned)E_idx[i];
        unsigned bits = __float_as_uint(scores[i]);
        unsigned pos = atomicAdd(&bh[e >> 8], 1u);
        pairs[pos] = pack_pair(e & 255u, bits, (unsigned)i);
    }
}

// ========== K4: hist1 + last-block scan1 (ticket, r6-proven pattern) ==========
__global__ __launch_bounds__(256) void hist1scan(const float4* __restrict__ scores4,
        unsigned* __restrict__ hist1g, unsigned* __restrict__ ticket,
        unsigned* __restrict__ sel, const int* __restrict__ kptr, int n4, int nnz) {
    __shared__ unsigned h[4096];
    __shared__ unsigned sfx[256];
    __shared__ unsigned isLast;
    int t = threadIdx.x;
    for (int j = t; j < 4096; j += 256) h[j] = 0;
    __syncthreads();
    unsigned r1016 = 0, r1015 = 0, r0 = 0;
    int stride = gridDim.x * 256;
    for (int i = blockIdx.x * 256 + t; i < n4; i += stride) {
        float4 sv = scores4[i];
        unsigned bb[4] = {__float_as_uint(sv.x), __float_as_uint(sv.y),
                          __float_as_uint(sv.z), __float_as_uint(sv.w)};
        #pragma unroll
        for (int q = 0; q < 4; ++q) {
            unsigned b = bb[q] >> 20;
            if (b == 1016) ++r1016;
            else if (b == 1015) ++r1015;
            else if (b == 0) ++r0;
            else atomicAdd(&h[b], 1u);
        }
    }
    for (int i = n4 * 4 + blockIdx.x * 256 + t; i < nnz; i += stride) {
        unsigned b = __float_as_uint(((const float*)scores4)[i]) >> 20;
        if (b == 1016) ++r1016;
        else if (b == 1015) ++r1015;
        else if (b == 0) ++r0;
        else atomicAdd(&h[b], 1u);
    }
    if (r1016) atomicAdd(&h[1016], r1016);
    if (r1015) atomicAdd(&h[1015], r1015);
    if (r0) atomicAdd(&h[0], r0);
    __syncthreads();
    for (int j = t; j < 4096; j += 256)
        if (h[j]) atomicAdd(&hist1g[j], h[j]);
    __threadfence();
    if (t == 0) isLast = (atomicAdd(ticket, 1u) == gridDim.x - 1) ? 1u : 0u;
    __syncthreads();
    if (!isLast) return;
    // ---- scan1 on final histogram (atomic reads for coherence) ----
    unsigned local[16];
    unsigned s = 0;
    #pragma unroll
    for (int j = 0; j < 16; ++j) { local[j] = atomicAdd(&hist1g[t * 16 + j], 0u); s += local[j]; }
    sfx[t] = s;
    __syncthreads();
    for (int off = 1; off < 256; off <<= 1) {
        unsigned add = (t + off < 256) ? sfx[t + off] : 0;
        __syncthreads();
        sfx[t] += add;
        __syncthreads();
    }
    unsigned krem = (unsigned)(*kptr);
    unsigned above = (t + 1 < 256) ? sfx[t + 1] : 0;
    if (above < krem && sfx[t] >= krem) {
        unsigned cum = above;
        int b = t * 16;
        for (int j = 15; j >= 0; --j) {
            unsigned cc = local[j];
            if (cum + cc >= krem) { b = t * 16 + j; break; }
            cum += cc;
        }
        sel[0] = krem - cum;
        sel[1] = ((unsigned)b) << 20;
    }
}

// ========== K5: compact candidates ==========
__global__ void compact_kernel(const float4* __restrict__ scores4,
                               const unsigned* __restrict__ sel,
                               uint2* __restrict__ cand, unsigned* __restrict__ candCount,
                               int n4, int nnz) {
    unsigned pref = sel[1] >> 20;
    int tid = blockIdx.x * blockDim.x + threadIdx.x;
    int stride = gridDim.x * blockDim.x;
    int lane = threadIdx.x & 63;
    int niter = (n4 + stride - 1) / stride;
    for (int kk = 0; kk < niter; ++kk) {
        int i = tid + kk * stride;
        bool inb = (i < n4);
        float4 sv = make_float4(0.f, 0.f, 0.f, 0.f);
        if (inb) sv = scores4[i];
        unsigned bb[4] = {__float_as_uint(sv.x), __float_as_uint(sv.y),
                          __float_as_uint(sv.z), __float_as_uint(sv.w)};
        #pragma unroll
        for (int q = 0; q < 4; ++q) {
            bool pred = inb && ((bb[q] >> 20) == pref);
            unsigned long long mask = __ballot(pred);
            if (mask) {
                int leader = __ffsll(mask) - 1;
                unsigned base = 0;
                if (lane == leader) base = atomicAdd(candCount, (unsigned)__popcll(mask));
                base = __shfl(base, leader, 64);
                if (pred) {
                    unsigned rank = __popcll(mask & ((1ull << lane) - 1ull));
                    unsigned pos = base + rank;
                    if (pos < CAND_CAP) cand[pos] = make_uint2(bb[q], (unsigned)(i * 4 + q));
                }
            }
        }
    }
    for (int i = n4 * 4 + tid; i < nnz; i += stride) {
        unsigned b = __float_as_uint(((const float*)scores4)[i]);
        if ((b >> 20) == pref) {
            unsigned pos = atomicAdd(candCount, 1u);
            if (pos < CAND_CAP) cand[pos] = make_uint2(b, (unsigned)i);
        }
    }
}

// ========== K6: single-block selection among candidates ==========
__global__ __launch_bounds__(256) void select_small(const uint2* __restrict__ cand,
                            const unsigned* __restrict__ candCount,
                            unsigned* __restrict__ sel, unsigned* __restrict__ tieList) {
    __shared__ unsigned h2[4096];
    __shared__ unsigned sfx[256];
    __shared__ unsigned sB2, sKrem2, sT, sM;
    __shared__ unsigned h3[256];
    __shared__ unsigned ties[TIE_CAP];
    __shared__ unsigned tcnt;
    int t = threadIdx.x;
    unsigned nc = *candCount;
    int n = (nc < CAND_CAP) ? (int)nc : CAND_CAP;
    unsigned krem = sel[0];
    unsigned pref = sel[1];

    for (int j = t; j < 4096; j += 256) h2[j] = 0;
    if (t == 0) tcnt = 0;
    __syncthreads();
    for (int j = t; j < n; j += 256) atomicAdd(&h2[(cand[j].x >> 8) & 0xFFF], 1u);
    __syncthreads();

    unsigned local[16];
    unsigned s = 0;
    #pragma unroll
    for (int j = 0; j < 16; ++j) { local[j] = h2[t * 16 + j]; s += local[j]; }
    sfx[t] = s;
    __syncthreads();
    for (int off = 1; off < 256; off <<= 1) {
        unsigned add = (t + off < 256) ? sfx[t + off] : 0;
        __syncthreads();
        sfx[t] += add;
        __syncthreads();
    }
    {
        unsigned above = (t + 1 < 256) ? sfx[t + 1] : 0;
        if (above < krem && sfx[t] >= krem) {
            unsigned cum = above;
            int b = t * 16;
            for (int j = 15; j >= 0; --j) {
                unsigned cc = local[j];
                if (cum + cc >= krem) { b = t * 16 + j; break; }
                cum += cc;
            }
            sB2 = (unsigned)b;
            sKrem2 = krem - cum;
        }
    }
    __syncthreads();

    h3[t] = 0;
    __syncthreads();
    unsigned b2 = sB2;
    for (int j = t; j < n; j += 256) {
        unsigned x = cand[j].x;
        if (((x >> 8) & 0xFFF) == b2) atomicAdd(&h3[x & 0xFF], 1u);
    }
    __syncthreads();
    sfx[t] = h3[t];
    __syncthreads();
    for (int off = 1; off < 256; off <<= 1) {
        unsigned add = (t + off < 256) ? sfx[t + off] : 0;
        __syncthreads();
        sfx[t] += add;
        __syncthreads();
    }
    {
        unsigned krem2 = sKrem2;
        unsigned above = (t + 1 < 256) ? sfx[t + 1] : 0;
        if (above < krem2 && sfx[t] >= krem2) {
            sT = pref | (b2 << 8) | (unsigned)t;
            sM = krem2 - above;
        }
    }
    __syncthreads();

    unsigned T = sT;
    for (int j = t; j < n; j += 256) {
        if (cand[j].x == T) {
            unsigned p = atomicAdd(&tcnt, 1u);
            if (p < TIE_CAP) ties[p] = cand[j].y;
        }
    }
    __syncthreads();
    if (t == 0) {
        unsigned cnt = (tcnt < TIE_CAP) ? tcnt : TIE_CAP;
        for (unsigned a = 1; a < cnt; ++a) {
            unsigned key = ties[a];
            int bpos = (int)a - 1;
            while (bpos >= 0 && ties[bpos] > key) { ties[bpos + 1] = ties[bpos]; --bpos; }
            ties[bpos + 1] = key;
        }
        unsigned m = sM;
        if (m > cnt) m = cnt;
        sel[2] = T;
        sel[3] = m;
        for (unsigned j = 0; j < m; ++j) tieList[j] = ties[j];
    }
}

// ========== K7 (wsHuge): fused edge_final + write_hard — pairs in d_ws, no aliasing ==========
__global__ __launch_bounds__(256) void final_combo(const u64* __restrict__ pairs,
        const unsigned* __restrict__ bucketBase, const unsigned* __restrict__ sel,
        const unsigned* __restrict__ tieList, const float4* __restrict__ scores4,
        float* __restrict__ eprob, float* __restrict__ esoft, float* __restrict__ ehard,
        float4* __restrict__ hard4, float4* __restrict__ soft4,
        int nb, int n4, int nnz, int nhe) {
    __shared__ float ss[256];
    __shared__ unsigned cc[256];
    __shared__ unsigned hh[256];
    __shared__ unsigned ties[TIE_CAP];
    unsigned T = sel[2];
    unsigned m = sel[3];
    if (m > TIE_CAP) m = TIE_CAP;
    int t = threadIdx.x;
    for (int j = t; j < (int)m; j += 256) ties[j] = tieList[j];

    if ((int)blockIdx.x < nb) {
        ss[t] = 0.f; cc[t] = 0u; hh[t] = 0u;
        __syncthreads();
        int b = blockIdx.x;
        unsigned n0 = bucketBase[b], n1 = bucketBase[b + 1];
        for (unsigned j = n0 + t; j < n1; j += 256) {
            u64 p = pairs[j];
            unsigned el = (unsigned)(p >> 56);
            unsigned bits = (unsigned)(p >> 26) & 0x3FFFFFFFu;
            atomicAdd(&ss[el], __uint_as_float(bits));
            atomicAdd(&cc[el], 1u);
            bool keep = bits > T;
            if (bits == T) {
                unsigned idx = (unsigned)(p & 0x3FFFFFFu);
                int lo = 0, hi = (int)m - 1;
                keep = false;
                while (lo <= hi) {
                    int mid = (lo + hi) >> 1;
                    unsigned v = ties[mid];
                    if (v == idx) { keep = true; break; }
                    if (v < idx) lo = mid + 1; else hi = mid - 1;
                }
            }
            if (keep) atomicAdd(&hh[el], 1u);
        }
        __syncthreads();
        int e = blockIdx.x * 256 + t;
        if (e < nhe) {
            float c = fmaxf((float)cc[t], 1.0f);
            eprob[e] = ss[t] / c;
            esoft[e] = (float)hh[t] / c;
            ehard[e] = (hh[t] > 0) ? 1.0f : 0.0f;
        }
        return;
    }
    __syncthreads();
    int tid = (blockIdx.x - nb) * 256 + t;
    int stride = NW_BLOCKS * 256;
    for (int i = tid; i < n4; i += stride) {
        float4 sv = scores4[i];
        unsigned bb[4] = {__float_as_uint(sv.x), __float_as_uint(sv.y),
                          __float_as_uint(sv.z), __float_as_uint(sv.w)};
        float hv[4];
        #pragma unroll
        for (int q = 0; q < 4; ++q) {
            bool keep = (bb[q] > T);
            if (bb[q] == T) {
                unsigned idx = (unsigned)(i * 4 + q);
                int lo = 0, hi = (int)m - 1;
                keep = false;
                while (lo <= hi) {
                    int mid = (lo + hi) >> 1;
                    unsigned v = ties[mid];
                    if (v == idx) { keep = true; break; }
                    if (v < idx) lo = mid + 1; else hi = mid - 1;
                }
            }
            hv[q] = keep ? 1.0f : 0.0f;
        }
        float4 outv = make_float4(hv[0], hv[1], hv[2], hv[3]);
        hard4[i] = outv;
        soft4[i] = outv;
    }
    const float* sc = (const float*)scores4;
    float* hard = (float*)hard4;
    float* soft = (float*)soft4;
    for (int i = n4 * 4 + tid; i < nnz; i += stride) {
        unsigned b = __float_as_uint(sc[i]);
        bool keep = (b > T);
        if (b == T) {
            unsigned idx = (unsigned)i;
            int lo = 0, hi = (int)m - 1;
            keep = false;
            while (lo <= hi) {
                int mid = (lo + hi) >> 1;
                unsigned v = ties[mid];
                if (v == idx) { keep = true; break; }
                if (v < idx) lo = mid + 1; else hi = mid - 1;
            }
        }
        float hvv = keep ? 1.0f : 0.0f;
        hard[i] = hvv;
        soft[i] = hvv;
    }
}

// ========== K7b/K7c (fallback when pairs aliases soft/hard): sequential versions ==========
__global__ __launch_bounds__(256) void edge_final(const u64* __restrict__ pairs,
        const unsigned* __restrict__ bucketBase, const unsigned* __restrict__ sel,
        const unsigned* __restrict__ tieList,
        float* __restrict__ eprob, float* __restrict__ esoft, float* __restrict__ ehard,
        int nhe) {
    __shared__ float ss[256];
    __shared__ unsigned cc[256];
    __shared__ unsigned hh[256];
    __shared__ unsigned ties[TIE_CAP];
    unsigned T = sel[2];
    unsigned m = sel[3];
    if (m > TIE_CAP) m = TIE_CAP;
    int t = threadIdx.x;
    ss[t] = 0.f; cc[t] = 0u; hh[t] = 0u;
    for (int j = t; j < (int)m; j += 256) ties[j] = tieList[j];
    __syncthreads();
    int b = blockIdx.x;
    unsigned n0 = bucketBase[b], n1 = bucketBase[b + 1];
    for (unsigned j = n0 + t; j < n1; j += 256) {
        u64 p = pairs[j];
        unsigned el = (unsigned)(p >> 56);
        unsigned bits = (unsigned)(p >> 26) & 0x3FFFFFFFu;
        atomicAdd(&ss[el], __uint_as_float(bits));
        atomicAdd(&cc[el], 1u);
        bool keep = bits > T;
        if (bits == T) {
            unsigned idx = (unsigned)(p & 0x3FFFFFFu);
            int lo = 0, hi = (int)m - 1;
            keep = false;
            while (lo <= hi) {
                int mid = (lo + hi) >> 1;
                unsigned v = ties[mid];
                if (v == idx) { keep = true; break; }
                if (v < idx) lo = mid + 1; else hi = mid - 1;
            }
        }
        if (keep) atomicAdd(&hh[el], 1u);
    }
    __syncthreads();
    int e = b * 256 + t;
    if (e < nhe) {
        float c = fmaxf((float)cc[t], 1.0f);
        eprob[e] = ss[t] / c;
        esoft[e] = (float)hh[t] / c;
        ehard[e] = (hh[t] > 0) ? 1.0f : 0.0f;
    }
}
__global__ __launch_bounds__(256) void write_hard(const float4* __restrict__ scores4,
                           const unsigned* __restrict__ sel,
                           const unsigned* __restrict__ tieList,
                           float4* __restrict__ hard4, float4* __restrict__ soft4,
                           int n4, int nnz) {
    __shared__ unsigned ties[TIE_CAP];
    unsigned T = sel[2];
    unsigned m = sel[3];
    if (m > TIE_CAP) m = TIE_CAP;
    for (int j = threadIdx.x; j < (int)m; j += blockDim.x) ties[j] = tieList[j];
    __syncthreads();
    int tid = blockIdx.x * blockDim.x + threadIdx.x;
    int stride = gridDim.x * blockDim.x;
    for (int i = tid; i < n4; i += stride) {
        float4 sv = scores4[i];
        unsigned bb[4] = {__float_as_uint(sv.x), __float_as_uint(sv.y),
                          __float_as_uint(sv.z), __float_as_uint(sv.w)};
        float hv[4];
        #pragma unroll
        for (int q = 0; q < 4; ++q) {
            bool keep = (bb[q] > T);
            if (bb[q] == T) {
                unsigned idx = (unsigned)(i * 4 + q);
                int lo = 0, hi = (int)m - 1;
                keep = false;
                while (lo <= hi) {
                    int mid = (lo + hi) >> 1;
                    unsigned v = ties[mid];
                    if (v == idx) { keep = true; break; }
                    if (v < idx) lo = mid + 1; else hi = mid - 1;
                }
            }
            hv[q] = keep ? 1.0f : 0.0f;
        }
        float4 outv = make_float4(hv[0], hv[1], hv[2], hv[3]);
        hard4[i] = outv;
        soft4[i] = outv;
    }
    const float* sc = (const float*)scores4;
    float* hard = (float*)hard4;
    float* soft = (float*)soft4;
    for (int i = n4 * 4 + tid; i < nnz; i += stride) {
        unsigned b = __float_as_uint(sc[i]);
        bool keep = (b > T);
        if (b == T) {
            unsigned idx = (unsigned)i;
            int lo = 0, hi = (int)m - 1;
            keep = false;
            while (lo <= hi) {
                int mid = (lo + hi) >> 1;
                unsigned v = ties[mid];
                if (v == idx) { keep = true; break; }
                if (v < idx) lo = mid + 1; else hi = mid - 1;
            }
        }
        float hvv = keep ? 1.0f : 0.0f;
        hard[i] = hvv;
        soft[i] = hvv;
    }
}

extern "C" void kernel_launch(void* const* d_in, const int* in_sizes, int n_in,
                              void* d_out, int out_size, void* d_ws, size_t ws_size,
                              hipStream_t stream) {
    const float* x        = (const float*)d_in[0];
    const float* Wm       = (const float*)d_in[1];
    const float* ef       = (const float*)d_in[2];
    const int*   V_idx    = (const int*)d_in[3];
    const int*   E_idx    = (const int*)d_in[4];
    const int*   edge_ids = (const int*)d_in[5];
    const int*   kptr     = (const int*)d_in[6];

    const int nnz     = in_sizes[3];
    const int nhe     = in_sizes[5];
    const int n_nodes = in_sizes[0] / FEAT;
    const int nb      = (nhe + 255) >> 8;

    float* out    = (float*)d_out;
    float* scores = out;
    float* soft   = out + (size_t)nnz;
    float* hard   = out + 2 * (size_t)nnz;
    float* eprob  = out + 3 * (size_t)nnz;
    float* esoft  = eprob + nhe;
    float* ehard  = esoft + nhe;

    uint2* cand = (uint2*)eprob;   // consumed by select before eprob is written

    // ---- aux zone in d_ws ----
    char* w = (char*)d_ws;
    unsigned* hist1      = (unsigned*)w;               // 4096 (zeroed)
    unsigned* bucketCnt  = hist1 + 4096;               // NBK_MAX (zeroed)
    unsigned* candCount  = bucketCnt + NBK_MAX;        // 1 (zeroed)
    unsigned* ticket1    = candCount + 1;              // 1 (zeroed)  prep_all
    unsigned* ticket2    = ticket1 + 1;                // 1 (zeroed)  hist1scan
    unsigned* sel        = ticket2 + 1;                // 8
    unsigned* tieList    = sel + 8;                    // TIE_CAP
    unsigned* bucketBase = tieList + TIE_CAP;          // NBK_MAX+1
    unsigned* cursor     = bucketBase + NBK_MAX + 1;   // NBK_MAX
    char* auxEnd = (char*)(cursor + NBK_MAX);
    size_t auxAligned = (((size_t)(auxEnd - w)) + 255) & ~(size_t)255;
    size_t zeroBytes = (size_t)(4096 + NBK_MAX + 3) * sizeof(unsigned);

    size_t ef2Bytes   = (size_t)nhe * RANKK * sizeof(float);
    size_t projBytes  = (size_t)n_nodes * RANKK * sizeof(float);
    size_t pairsBytes = (size_t)nnz * sizeof(u64);

    bool wsBig  = (ws_size >= auxAligned + ef2Bytes + projBytes);
    bool wsHuge = (ws_size >= auxAligned + ef2Bytes + projBytes + pairsBytes);

    float* ef2;
    float* proj;
    u64*   vlist;
    if (wsBig) {
        ef2  = (float*)(w + auxAligned);
        proj = (float*)(w + auxAligned + ef2Bytes);
        vlist = wsHuge ? (u64*)(w + auxAligned + ef2Bytes + projBytes) : (u64*)soft;
    } else {
        ef2  = hard;   // consumed by score before pairs scatter touches hard
        proj = hard + (size_t)nhe * RANKK;
        vlist = (u64*)soft;
    }

    hipMemsetAsync(w, 0, zeroBytes, stream);

    int G = (nhe * 4 + 255) / 256;
    int P = (n_nodes + PRJ_NODES - 1) / PRJ_NODES;
    prep_all<<<EH_BLOCKS + G + P, 256, 0, stream>>>(
        E_idx, bucketCnt, bucketBase, cursor, ticket1, nnz,
        (const float4*)ef, edge_ids, (float4*)ef2, nhe,
        x, Wm, proj, n_nodes, G);

    int nChunks = (nnz + PB_CHUNK - 1) / PB_CHUNK;
    if (wsBig) {
        sort_kernel<<<nChunks, 256, 0, stream>>>(V_idx, E_idx, vlist, cursor, nnz, nb);
        bucket_score<<<nb * SPLIT, 256, 0, stream>>>(
            (const float4*)proj, (const float4*)ef2, bucketBase, vlist, scores, nhe);
    } else {
        score_linear<<<2048, 256, 0, stream>>>(
            (const float4*)proj, (const float4*)ef2, V_idx, E_idx, scores, nnz);
        pair_build<<<nChunks, 256, 0, stream>>>(E_idx, scores, vlist, cursor, nnz, nb);
    }

    int n4 = nnz / 4;
    hist1scan<<<128, 256, 0, stream>>>((const float4*)scores, hist1, ticket2,
                                       sel, kptr, n4, nnz);
    compact_kernel<<<1024, 256, 0, stream>>>(
        (const float4*)scores, sel, cand, candCount, n4, nnz);
    select_small<<<1, 256, 0, stream>>>(cand, candCount, sel, tieList);

    if (wsHuge) {
        final_combo<<<nb + NW_BLOCKS, 256, 0, stream>>>(
            vlist, bucketBase, sel, tieList, (const float4*)scores,
            eprob, esoft, ehard, (float4*)hard, (float4*)soft, nb, n4, nnz, nhe);
    } else {
        edge_final<<<nb, 256, 0, stream>>>(vlist, bucketBase, sel, tieList,
                                           eprob, esoft, ehard, nhe);
        write_hard<<<1024, 256, 0, stream>>>(
            (const float4*)scores, sel, tieList, (float4*)hard, (float4*)soft, n4, nnz);
    }
}